// Round 13
// baseline (378.896 us; speedup 1.0000x reference)
//
#include <hip/hip_runtime.h>
#include <hip/hip_bf16.h>

#define T_SEQ 2048
#define HID_DIM 2048

typedef __attribute__((ext_vector_type(8))) short short8;
typedef __attribute__((ext_vector_type(4))) short short4v;
typedef __attribute__((ext_vector_type(4))) float f32x4;

#define MFMA16(a, b, c) __builtin_amdgcn_mfma_f32_16x16x32_bf16((a), (b), (c), 0, 0, 0)

static __device__ __forceinline__ ushort f2bf(float f) {
  union { __hip_bfloat16 h; ushort u; } un;
  un.h = __float2bfloat16(f);
  return un.u;
}
static __device__ __forceinline__ float bf2f(ushort u) {
  union { ushort u; __hip_bfloat16 h; } un;
  un.u = u;
  return __bfloat162float(un.h);
}

static __device__ __forceinline__ void gload_lds16(const void* g, void* l) {
  __builtin_amdgcn_global_load_lds(
      (const __attribute__((address_space(1))) void*)g,
      (__attribute__((address_space(3))) void*)l, 16, 0, 0);
}

// ---------------- fp32 -> bf16 cast (float4 vectorized) ----------------
__global__ __launch_bounds__(256) void cast_kernel(const float* __restrict__ in,
                                                   ushort* __restrict__ out, int n4) {
  int i = blockIdx.x * 256 + threadIdx.x;
  if (i >= n4) return;
  const float4 v = reinterpret_cast<const float4*>(in)[i];
  ushort4 o;
  o.x = f2bf(v.x); o.y = f2bf(v.y); o.z = f2bf(v.z); o.w = f2bf(v.w);
  reinterpret_cast<ushort4*>(out)[i] = o;
}

// ---------------- 256-tile GEMM, per-phase interleaved schedule ----------
// Fine-grained phases (T3 prerequisite for T2/T4/T5). Per K-tile: NPHT
// phases of {issue LPP next-tile global_load_lds; ds_read quadrant frags;
// s_barrier; setprio1; 16 MFMA; setprio0}. Loop-top: s_waitcnt vmcnt(0)
// (loads issued 2-4 phases earlier -> cheap) + s_barrier (guards buffer
// reuse: staging at tile kt targets bf^1, whose tile-(kt-1) readers all
// passed this barrier).
__device__ __forceinline__ void store_c(float* p, float v) { *p = v; }
__device__ __forceinline__ void store_c(ushort* p, float v) { *p = f2bf(v); }

template <int MODE, int BN, typename OutT>
__global__ __launch_bounds__(512) void gemm8p(const ushort* __restrict__ A,
                                              const ushort* __restrict__ W,
                                              OutT* __restrict__ C,
                                              ushort* __restrict__ vTout,
                                              int M, int N, int K) {
  constexpr int LA = 4;            // A staging chunks/thread/K-tile
  constexpr int LB = BN / 64;      // B staging chunks/thread/K-tile
  constexpr int NR = BN / 64;      // 16-col fragments per wave
  constexpr int NPHT = 2 * (NR / 2);      // phases per K-tile (4 or 2)
  constexpr int LPP = (LA + LB) / NPHT;   // staging issues per phase (2 or 3)
  __shared__ __align__(16) ushort As[2][256 * 64];
  __shared__ __align__(16) ushort Bs[2][BN * 64];
  const int tid = threadIdx.x;
  const int lane = tid & 63, l15 = lane & 15, lhi = lane >> 4;
  const int wid = tid >> 6, wm = wid >> 2, wn = wid & 3;
  const int brow = blockIdx.y * 256, bcol = blockIdx.x * BN;
  const int nkt = K >> 6;

  const ushort* asrc[LA]; ushort* adst[LA];
#pragma unroll
  for (int j = 0; j < LA; ++j) {
    const int c = tid + 512 * j, row = c >> 3, k16 = c & 7;
    asrc[j] = A + (size_t)(brow + row) * K + ((k16 ^ (row & 7)) << 3);
    adst[j] = &As[0][0] + c * 8;
  }
  const ushort* bsrc[LB]; ushort* bdst[LB];
#pragma unroll
  for (int j = 0; j < LB; ++j) {
    const int c = tid + 512 * j, row = c >> 3, k16 = c & 7;
    bsrc[j] = W + (size_t)(bcol + row) * K + ((k16 ^ (row & 7)) << 3);
    bdst[j] = &Bs[0][0] + c * 8;
  }

  f32x4 acc[8][NR] = {};

  // prologue: stage tile 0 into buffer 0
#pragma unroll
  for (int j = 0; j < LA; ++j) gload_lds16(asrc[j], adst[j]);
#pragma unroll
  for (int j = 0; j < LB; ++j) gload_lds16(bsrc[j], bdst[j]);

  for (int kt = 0; kt < nkt; ++kt) {
    const int bufi = kt & 1;
    asm volatile("s_waitcnt vmcnt(0)" ::: "memory");
    __builtin_amdgcn_s_barrier();
    const char* abuf = (const char*)&As[bufi][0];
    const char* bbuf = (const char*)&Bs[bufi][0];
    const bool pf = (kt + 1 < nkt);
#pragma unroll
    for (int mh = 0; mh < 2; ++mh) {
#pragma unroll
      for (int nhh = 0; nhh < NR / 2; ++nhh) {
        const int ph = mh * (NR / 2) + nhh;
        // issue this phase's share of next-tile staging (into bufi^1)
        if (pf) {
#pragma unroll
          for (int i = 0; i < LPP; ++i) {
            const int f = ph * LPP + i;
            if (f < LA)
              gload_lds16(asrc[f] + (kt + 1) * 64,
                          adst[f] + (bufi ^ 1) * (256 * 64));
            else
              gload_lds16(bsrc[f - LA] + (kt + 1) * 64,
                          bdst[f - LA] + (bufi ^ 1) * (BN * 64));
          }
        }
        // fragment reads for this quadrant
        short8 af_[4][2];
#pragma unroll
        for (int mi = 0; mi < 4; ++mi) {
          const int row = wm * 128 + (mh * 4 + mi) * 16 + l15;
          const int sw = (row & 7) << 4;
#pragma unroll
          for (int ks = 0; ks < 2; ++ks)
            af_[mi][ks] = *(const short8*)(abuf + row * 128 +
                                           ((ks * 64 + lhi * 16) ^ sw));
        }
        short8 bq_[2][2];
#pragma unroll
        for (int ni = 0; ni < 2; ++ni) {
          const int rowb = wn * (BN / 4) + (nhh * 2 + ni) * 16 + l15;
          const int sw = (rowb & 7) << 4;
#pragma unroll
          for (int ks = 0; ks < 2; ++ks)
            bq_[ni][ks] = *(const short8*)(bbuf + rowb * 128 +
                                           ((ks * 64 + lhi * 16) ^ sw));
        }
        __builtin_amdgcn_s_barrier();
        __builtin_amdgcn_s_setprio(1);
#pragma unroll
        for (int ks = 0; ks < 2; ++ks)
#pragma unroll
          for (int mi = 0; mi < 4; ++mi)
#pragma unroll
            for (int ni = 0; ni < 2; ++ni)
              acc[mh * 4 + mi][nhh * 2 + ni] =
                  MFMA16(af_[mi][ks], bq_[ni][ks],
                         acc[mh * 4 + mi][nhh * 2 + ni]);
        __builtin_amdgcn_s_setprio(0);
      }
    }
  }

  if (MODE == 2 && bcol >= 2560) {
    // V projection -> vT[(b*8+hkv)*64 + d][t]
#pragma unroll
    for (int mi8 = 0; mi8 < 8; ++mi8) {
      const int row = brow + wm * 128 + mi8 * 16 + lhi * 4;
      const int bb = row >> 11, t = row & 2047;
#pragma unroll
      for (int ni = 0; ni < NR; ++ni) {
        const int cv = bcol + wn * (BN / 4) + ni * 16 + l15 - 2560;
        const int hk = cv >> 6, dd = cv & 63;
        ushort4 o;
        o.x = f2bf(acc[mi8][ni][0]); o.y = f2bf(acc[mi8][ni][1]);
        o.z = f2bf(acc[mi8][ni][2]); o.w = f2bf(acc[mi8][ni][3]);
        *(ushort4*)&vTout[(size_t)((bb * 8 + hk) * 64 + dd) * 2048 + t] = o;
      }
    }
  } else {
    const int cstride = (MODE == 2) ? 2560 : N;
#pragma unroll
    for (int mi8 = 0; mi8 < 8; ++mi8) {
      const int row = brow + wm * 128 + mi8 * 16 + lhi * 4;
#pragma unroll
      for (int ni = 0; ni < NR; ++ni) {
        const int col = bcol + wn * (BN / 4) + ni * 16 + l15;
#pragma unroll
        for (int r = 0; r < 4; ++r)
          store_c(&C[(size_t)(row + r) * cstride + col], acc[mi8][ni][r]);
      }
    }
  }
}

// ---------------- RoPE in-place on QK buffer (stride 2560); Q pre-scaled -
__global__ __launch_bounds__(256) void rope_kernel(ushort* __restrict__ qkv,
                                                   const float* __restrict__ ct,
                                                   const float* __restrict__ st) {
  const int bt = blockIdx.x;
  ushort* row = qkv + (size_t)bt * 2560;
  const float* c = ct + (size_t)bt * 64;
  const float* s = st + (size_t)bt * 64;
  const int tid = threadIdx.x;
#pragma unroll
  for (int it = 0; it < 5; ++it) {
    const int idx = it * 256 + tid;
    const bool isQ = idx < 1024;
    const int sub = isQ ? idx : idx - 1024;
    const int hh = sub >> 5;
    const int p = sub & 31;
    const int col = (isQ ? 0 : 2048) + hh * 64 + p;
    const float x1 = bf2f(row[col]);
    const float x2 = bf2f(row[col + 32]);
    const float cc = c[p], ss = s[p];
    float y1 = x1 * cc - x2 * ss;
    float y2 = x2 * cc + x1 * ss;
    if (isQ) { y1 *= 0.125f; y2 *= 0.125f; }
    row[col] = f2bf(y1);
    row[col + 32] = f2bf(y2);
  }
}

// ---------------- causal GQA flash attention ---------------------------
// K/V LDS double-buffered with prefetch + counted vmcnt + raw s_barrier
// (no __syncthreads -> no vmcnt(0) drain of prefetch); Pt XOR-swizzled
// ((q&7)<<4) to 8KB so LDS = 40KB = 4 blocks/CU; defer-max (T13): skip
// O-rescale when __all(mx <= m+8).
#define PROCESS(SUF, diag_) do {                                              \
    f32x4 s_[4] = {};                                                         \
    __builtin_amdgcn_s_setprio(1);                                            \
    _Pragma("unroll")                                                         \
    for (int n = 0; n < 4; ++n) {                                             \
      const short8 k0_ = *(const short8*)(KtB + bfo_ + n * 2048 + base0);     \
      const short8 k1_ = *(const short8*)(KtB + bfo_ + n * 2048 + base1);     \
      s_[n] = MFMA16(k0_, q##SUF##0, s_[n]);                                  \
      s_[n] = MFMA16(k1_, q##SUF##1, s_[n]);                                  \
    }                                                                         \
    __builtin_amdgcn_s_setprio(0);                                            \
    if (diag_) {                                                              \
      _Pragma("unroll")                                                       \
      for (int n = 0; n < 4; ++n) {                                           \
        const int kb_ = 16 * n + 4 * lhi;                                     \
        _Pragma("unroll")                                                     \
        for (int r = 0; r < 4; ++r)                                           \
          if (kb_ + r > qloc) s_[n][r] = -1e30f;                              \
      }                                                                       \
    }                                                                         \
    float mx_;                                                                \
    {                                                                         \
      const float m0_ = fmaxf(fmaxf(s_[0][0], s_[0][1]), fmaxf(s_[0][2], s_[0][3])); \
      const float m1_ = fmaxf(fmaxf(s_[1][0], s_[1][1]), fmaxf(s_[1][2], s_[1][3])); \
      const float m2_ = fmaxf(fmaxf(s_[2][0], s_[2][1]), fmaxf(s_[2][2], s_[2][3])); \
      const float m3_ = fmaxf(fmaxf(s_[3][0], s_[3][1]), fmaxf(s_[3][2], s_[3][3])); \
      mx_ = fmaxf(fmaxf(m0_, m1_), fmaxf(m2_, m3_));                          \
    }                                                                         \
    mx_ = fmaxf(mx_, __shfl_xor(mx_, 16));                                    \
    mx_ = fmaxf(mx_, __shfl_xor(mx_, 32));                                    \
    if (!__all(mx_ <= mS##SUF + 8.0f)) {    /* defer-max: rescale only if */  \
      const float mn_ = fmaxf(mS##SUF, mx_);                                  \
      const float al_ = __expf(mS##SUF - mn_);                                \
      mS##SUF = mn_;                                                          \
      lS##SUF *= al_;                                                         \
      const float al0_ = __shfl(al_, 4 * lhi + 0);                            \
      const float al1_ = __shfl(al_, 4 * lhi + 1);                            \
      const float al2_ = __shfl(al_, 4 * lhi + 2);                            \
      const float al3_ = __shfl(al_, 4 * lhi + 3);                            \
      _Pragma("unroll")                                                       \
      for (int n = 0; n < 4; ++n) {                                           \
        o##SUF[n][0] *= al0_;                                                 \
        o##SUF[n][1] *= al1_;                                                 \
        o##SUF[n][2] *= al2_;                                                 \
        o##SUF[n][3] *= al3_;                                                 \
      }                                                                       \
    }                                                                         \
    _Pragma("unroll")                                                         \
    for (int n = 0; n < 4; ++n) {                                             \
      s_[n][0] = __expf(s_[n][0] - mS##SUF);                                  \
      s_[n][1] = __expf(s_[n][1] - mS##SUF);                                  \
      s_[n][2] = __expf(s_[n][2] - mS##SUF);                                  \
      s_[n][3] = __expf(s_[n][3] - mS##SUF);                                  \
    }                                                                         \
    float rs_;                                                                \
    {                                                                         \
      const float t0_ = (s_[0][0] + s_[0][1]) + (s_[0][2] + s_[0][3]);        \
      const float t1_ = (s_[1][0] + s_[1][1]) + (s_[1][2] + s_[1][3]);        \
      const float t2_ = (s_[2][0] + s_[2][1]) + (s_[2][2] + s_[2][3]);        \
      const float t3_ = (s_[3][0] + s_[3][1]) + (s_[3][2] + s_[3][3]);        \
      rs_ = (t0_ + t1_) + (t2_ + t3_);                                        \
    }                                                                         \
    rs_ += __shfl_xor(rs_, 16);                                               \
    rs_ += __shfl_xor(rs_, 32);                                               \
    lS##SUF += rs_;                                                           \
    _Pragma("unroll")                                                         \
    for (int n = 0; n < 4; ++n) {                                             \
      short4v pk_;                                                            \
      pk_[0] = (short)f2bf(s_[n][0]);                                         \
      pk_[1] = (short)f2bf(s_[n][1]);                                         \
      pk_[2] = (short)f2bf(s_[n][2]);                                         \
      pk_[3] = (short)f2bf(s_[n][3]);                                         \
      *(short4v*)(PtB + prow + ((32 * n + 8 * lhi) ^ psw)) = pk_;             \
    }                                                                         \
    {                                                                         \
      const short8 p0_ = *(const short8*)(PtB + prow + ((16 * lhi) ^ psw));   \
      const short8 p1_ = *(const short8*)(PtB + prow + ((64 + 16 * lhi) ^ psw)); \
      __builtin_amdgcn_s_setprio(1);                                          \
      _Pragma("unroll")                                                       \
      for (int n = 0; n < 4; ++n) {                                           \
        const short8 v0_ = *(const short8*)(VtB + bfo_ + n * 2048 + base0);   \
        const short8 v1_ = *(const short8*)(VtB + bfo_ + n * 2048 + base1);   \
        o##SUF[n] = MFMA16(p0_, v0_, o##SUF[n]);                              \
        o##SUF[n] = MFMA16(p1_, v1_, o##SUF[n]);                              \
      }                                                                       \
      __builtin_amdgcn_s_setprio(0);                                          \
    }                                                                         \
  } while (0)

__global__ __launch_bounds__(256) void attn_kernel(const ushort* __restrict__ qkv,
                                                   const ushort* __restrict__ vT,
                                                   ushort* __restrict__ out) {
  __shared__ __align__(16) ushort Kt[2][4096];  // [buf][kv][d] 64x64 swizzled
  __shared__ __align__(16) ushort Vt[2][4096];  // [buf][d][kv] 64x64 swizzled
  __shared__ __align__(16) ushort Pt[4096];     // [q][k] 64x64, XOR-swizzled
  const int bid = blockIdx.x;
  const int j = bid >> 3;
  const int bh = (bid & 7) * 8 + (j & 7);     // bijective over 0..63
  const int bx = j >> 3;                      // 0..15
  const int b = bh >> 5, h = bh & 31, hkv = h >> 2;
  const int tid = threadIdx.x;
  const int wid = tid >> 6, lane = tid & 63, l15 = lane & 15, lhi = lane >> 4;
  const int qA = bx, qB = 31 - bx;
  const int qloc = wid * 16 + l15;

  short8 qA0, qA1, qB0, qB1;
  {
    const size_t offA = (size_t)(b * T_SEQ + qA * 64 + qloc) * 2560 + h * 64;
    qA0 = *(const short8*)(qkv + offA + lhi * 8);
    qA1 = *(const short8*)(qkv + offA + 32 + lhi * 8);
    const size_t offB = (size_t)(b * T_SEQ + qB * 64 + qloc) * 2560 + h * 64;
    qB0 = *(const short8*)(qkv + offB + lhi * 8);
    qB1 = *(const short8*)(qkv + offB + 32 + lhi * 8);
  }

  f32x4 oA[4] = {}, oB[4] = {};
  float mSA = -1e30f, lSA = 0.f, mSB = -1e30f, lSB = 0.f;

  const int swb = (l15 & 7) << 4;
  const int base0 = l15 * 128 + ((lhi * 16) ^ swb);
  const int base1 = l15 * 128 + ((64 + lhi * 16) ^ swb);
  const char* KtB = (const char*)&Kt[0][0];
  const char* VtB = (const char*)&Vt[0][0];
  char* PtB = (char*)Pt;
  const int prow = qloc * 128;
  const int psw = (qloc & 7) << 4;

  const int srow = tid >> 3, sgrp = tid & 7;
  const int d0s = ((sgrp ^ (srow & 7)) * 8);
  const ushort* kb_g = qkv + (size_t)b * T_SEQ * 2560 + 2048 + hkv * 64;
  const ushort* vb_g = vT + (size_t)(b * 8 + hkv) * 64 * 2048;
  ushort* ldsK = &Kt[0][0] + tid * 8;
  ushort* ldsV = &Vt[0][0] + tid * 8;

  // prologue: stage tile 0 into buffer 0
  gload_lds16(kb_g + (size_t)srow * 2560 + d0s, ldsK);
  gload_lds16(kb_g + (size_t)(32 + srow) * 2560 + d0s, ldsK + 2048);
  gload_lds16(vb_g + (size_t)srow * 2048 + d0s, ldsV);
  gload_lds16(vb_g + (size_t)(32 + srow) * 2048 + d0s, ldsV + 2048);

  for (int kt = 0; kt <= qB; ++kt) {
    const int bufi = kt & 1;
    const int bfo_ = bufi << 13;  // byte offset into Kt/Vt
    if (kt < qB) {
      const int kt1 = (kt + 1) * 64;
      ushort* dK = ldsK + (bufi ^ 1) * 4096;
      ushort* dV = ldsV + (bufi ^ 1) * 4096;
      gload_lds16(kb_g + (size_t)(kt1 + srow) * 2560 + d0s, dK);
      gload_lds16(kb_g + (size_t)(kt1 + 32 + srow) * 2560 + d0s, dK + 2048);
      gload_lds16(vb_g + (size_t)srow * 2048 + kt1 + d0s, dV);
      gload_lds16(vb_g + (size_t)(32 + srow) * 2048 + kt1 + d0s, dV + 2048);
      asm volatile("s_waitcnt vmcnt(4)" ::: "memory");
    } else {
      asm volatile("s_waitcnt vmcnt(0)" ::: "memory");
    }
    __builtin_amdgcn_s_barrier();
    PROCESS(B, kt == qB);
    if (kt <= qA) PROCESS(A, kt == qA);
    __builtin_amdgcn_s_barrier();
  }

  {
    const float invA = 1.f / lSA;
    const float i0 = __shfl(invA, 4 * lhi + 0), i1 = __shfl(invA, 4 * lhi + 1);
    const float i2 = __shfl(invA, 4 * lhi + 2), i3 = __shfl(invA, 4 * lhi + 3);
    const size_t orow = (size_t)(b * T_SEQ + qA * 64 + wid * 16 + lhi * 4);
#pragma unroll
    for (int n = 0; n < 4; ++n) {
      out[(orow + 0) * 2048 + h * 64 + n * 16 + l15] = f2bf(oA[n][0] * i0);
      out[(orow + 1) * 2048 + h * 64 + n * 16 + l15] = f2bf(oA[n][1] * i1);
      out[(orow + 2) * 2048 + h * 64 + n * 16 + l15] = f2bf(oA[n][2] * i2);
      out[(orow + 3) * 2048 + h * 64 + n * 16 + l15] = f2bf(oA[n][3] * i3);
    }
  }
  {
    const float invB = 1.f / lSB;
    const float i0 = __shfl(invB, 4 * lhi + 0), i1 = __shfl(invB, 4 * lhi + 1);
    const float i2 = __shfl(invB, 4 * lhi + 2), i3 = __shfl(invB, 4 * lhi + 3);
    const size_t orow = (size_t)(b * T_SEQ + qB * 64 + wid * 16 + lhi * 4);
#pragma unroll
    for (int n = 0; n < 4; ++n) {
      out[(orow + 0) * 2048 + h * 64 + n * 16 + l15] = f2bf(oB[n][0] * i0);
      out[(orow + 1) * 2048 + h * 64 + n * 16 + l15] = f2bf(oB[n][1] * i1);
      out[(orow + 2) * 2048 + h * 64 + n * 16 + l15] = f2bf(oB[n][2] * i2);
      out[(orow + 3) * 2048 + h * 64 + n * 16 + l15] = f2bf(oB[n][3] * i3);
    }
  }
}

// -----------------------------------------------------------------------
extern "C" void kernel_launch(void* const* d_in, const int* in_sizes, int n_in,
                              void* d_out, int out_size, void* d_ws, size_t ws_size,
                              hipStream_t stream) {
  const float* hs   = (const float*)d_in[0];
  const float* cosb = (const float*)d_in[1];
  const float* sinb = (const float*)d_in[2];
  const float* wq   = (const float*)d_in[3];
  const float* wk   = (const float*)d_in[4];
  const float* wv   = (const float*)d_in[5];
  const float* wo   = (const float*)d_in[6];
  float* out = (float*)d_out;

  char* ws = (char*)d_ws;
  ushort* hsb   = (ushort*)(ws);                    // 4096x2048 bf16 (16 MB)
  ushort* wqkvb = (ushort*)(ws + 16777216);         // 3072x2048 bf16 (12.6 MB)
  ushort* wob   = (ushort*)(ws + 29360128);         // 2048x2048 bf16 (8.4 MB)
  ushort* qkvQK = (ushort*)(ws + 37748736);         // 4096x2560 bf16 (21 MB)
  ushort* vTb   = (ushort*)(ws + 58720256);         // 16x64x2048 bf16 (4 MB)
  ushort* attno = hsb;  // alias: hs_bf16 dead after QKV GEMM

  cast_kernel<<<8192, 256, 0, stream>>>(hs, hsb, 2097152);
  cast_kernel<<<4096, 256, 0, stream>>>(wq, wqkvb, 1048576);
  cast_kernel<<<1024, 256, 0, stream>>>(wk, wqkvb + 4194304, 262144);
  cast_kernel<<<1024, 256, 0, stream>>>(wv, wqkvb + 5242880, 262144);
  cast_kernel<<<4096, 256, 0, stream>>>(wo, wob, 1048576);

  // fused QKV projection (256x256 tiles); V columns routed transposed to vTb
  gemm8p<2, 256, ushort><<<dim3(12, 16), 512, 0, stream>>>(hsb, wqkvb, qkvQK,
                                                           vTb, 4096, 3072, 2048);

  rope_kernel<<<4096, 256, 0, stream>>>(qkvQK, cosb, sinb);

  attn_kernel<<<1024, 256, 0, stream>>>(qkvQK, vTb, attno);

  // output projection (256x128 tiles, exactly 1 block/CU) -> fp32 out
  gemm8p<0, 128, float><<<dim3(16, 16), 512, 0, stream>>>(attno, wob, out,
                                                          nullptr, 4096, 2048, 2048);
}